// Round 2
// baseline (327.526 us; speedup 1.0000x reference)
//
#include <hip/hip_runtime.h>
#include <stdint.h>

typedef unsigned long long u64;
typedef unsigned int u32;

#define FH 37
#define FW 62
#define NA 9
#define NPRED (FH*FW*NA)   // 20646
#define BS 4
#define KEEP_PRE 6000
#define KEEP_POST 300
#define NBINS 4096

// ws layout (bytes), all 16B aligned
#define OFF_KEYS    0u
#define OFF_BOXES   660672u
#define OFF_HIST    1982016u
#define OFF_NPOS    2047552u
#define OFF_SUFFIX  2047568u
#define OFF_CURSOR  2113104u
#define OFF_SORTED  2178640u
#define OFF_PROPS   2839312u
#define WS_NEEDED   3223312u

// ---------------------------------------------------------------------------
// Kernel 1: keys (order-exact sort key from pred bits) + box decode + histogram
// + per-batch positive-pred count (conf bit == rank < npos)
// ---------------------------------------------------------------------------
__global__ void __launch_bounds__(1024) prep_kernel(
    const float* __restrict__ preds, const float* __restrict__ regs,
    const int* __restrict__ ih, const int* __restrict__ iw,
    u64* __restrict__ keys, float4* __restrict__ boxes, u32* __restrict__ ghist,
    u32* __restrict__ nposg)
{
  __shared__ u32 lh[NBINS];
  const int tid = threadIdx.x;
  const int b = blockIdx.y;
  for (int v = tid; v < NBINS; v += 1024) lh[v] = 0;
  __syncthreads();
  const int n = blockIdx.x * 1024 + tid;
  const bool valid = (n < NPRED);
  float p = valid ? preds[b*NPRED + n] : -1.0f;

  // all 1024 lanes active here: wave-level count of strictly-positive preds
  u64 posmask = __ballot(valid && (p > 0.0f));
  if ((tid & 63) == 0) atomicAdd(&nposg[b], (u32)__popcll(posmask));

  if (valid) {
    u32 u = __float_as_uint(p);
    u32 m = (u & 0x80000000u) ? ~u : (u | 0x80000000u);  // order-preserving map
    u64 key = ((u64)m << 32) | (u32)(~(u32)n);           // tiebreak: lower idx first
    keys[b*NPRED + n] = key;
    atomicAdd(&lh[m >> 20], 1u);

    // decode box, mirroring reference op order
    int a = n % NA;
    int cell = n / NA;
    int x = cell % FW;
    int y = cell / FW;
    int si = a % 3, ri = a / 3;
    float s = (si==0) ? 8.f : ((si==1) ? 16.f : 32.f);
    float r = (ri==0) ? 0.5f : ((ri==1) ? 1.0f : 2.0f);
    float aw = s * sqrtf(1.0f / r);
    float ah = s * sqrtf(r);
    float gx = (float)x * 16.f, gy = (float)y * 16.f;
    float x1d = gx - 0.5f*aw, x2d = gx + 0.5f*aw;
    float y1d = gy - 0.5f*ah, y2d = gy + 0.5f*ah;
    float w = x2d - x1d, h = y2d - y1d;
    float cx = x1d + 0.5f*w, cy = y1d + 0.5f*h;
    float4 d = reinterpret_cast<const float4*>(regs)[b*NPRED + n];
    float pcx = d.x*w + cx, pcy = d.y*h + cy;
    float pw = expf(d.z)*w, ph = expf(d.w)*h;
    float W = (float)(*iw), H = (float)(*ih);
    float bx1 = fminf(fmaxf(pcx - 0.5f*pw, 0.f), W);
    float by1 = fminf(fmaxf(pcy - 0.5f*ph, 0.f), H);
    float bx2 = fminf(fmaxf(pcx + 0.5f*pw, 0.f), W);
    float by2 = fminf(fmaxf(pcy + 0.5f*ph, 0.f), H);
    boxes[b*NPRED + n] = make_float4(bx1, by1, bx2, by2);
  }
  __syncthreads();
  for (int v = tid; v < NBINS; v += 1024) {
    u32 c = lh[v];
    if (c) atomicAdd(&ghist[b*NBINS + v], c);
  }
}

// ---------------------------------------------------------------------------
// Kernel 2: per-batch suffix sum over bins (count of elements in higher bins)
// ---------------------------------------------------------------------------
__global__ void __launch_bounds__(1024) suffix_kernel(
    const u32* __restrict__ ghist, u32* __restrict__ gsuffix, u32* __restrict__ gcursor)
{
  __shared__ u32 vals[NBINS];
  __shared__ u32 psum[1024];
  const int b = blockIdx.x, t = threadIdx.x;
  for (int v = t; v < NBINS; v += 1024) vals[v] = ghist[b*NBINS + v];
  __syncthreads();
  u32 a0 = vals[4*t], a1 = vals[4*t+1], a2 = vals[4*t+2], a3 = vals[4*t+3];
  u32 s = a0 + a1 + a2 + a3;
  psum[t] = s;
  __syncthreads();
  for (int off = 1; off < 1024; off <<= 1) {
    u32 add = (t + off < 1024) ? psum[t + off] : 0;
    __syncthreads();
    psum[t] += add;
    __syncthreads();
  }
  u32 tail = psum[t] - s;        // sum over threads > t
  u32 s3 = tail;
  u32 s2 = s3 + a3;
  u32 s1 = s2 + a2;
  u32 s0 = s1 + a1;
  int base = b*NBINS + 4*t;
  gsuffix[base+0]=s0; gsuffix[base+1]=s1; gsuffix[base+2]=s2; gsuffix[base+3]=s3;
  gcursor[base+0]=s0; gcursor[base+1]=s1; gcursor[base+2]=s2; gcursor[base+3]=s3;
}

// ---------------------------------------------------------------------------
// Kernel 3: scatter keys into bin-ordered array (counting sort; in-bin order
// irrelevant — exact rank computed by comparison later)
// ---------------------------------------------------------------------------
__global__ void __launch_bounds__(1024) scatter_kernel(
    const u64* __restrict__ keys, u32* __restrict__ gcursor, u64* __restrict__ sorted)
{
  const int b = blockIdx.y;
  const int n = blockIdx.x*1024 + threadIdx.x;
  if (n >= NPRED) return;
  u64 k = keys[b*NPRED + n];
  u32 bin = (u32)(k >> 52);
  u32 pos = atomicAdd(&gcursor[b*NBINS + bin], 1u);
  sorted[b*NPRED + pos] = k;
}

// ---------------------------------------------------------------------------
// Kernel 4: exact rank (bin base + in-bin count of larger keys); gather props
// ---------------------------------------------------------------------------
__global__ void __launch_bounds__(1024) rank_kernel(
    const u64* __restrict__ sorted, const u32* __restrict__ gsuffix,
    const u32* __restrict__ ghist, const float4* __restrict__ boxes,
    float4* __restrict__ props)
{
  const int b = blockIdx.y;
  const int p = blockIdx.x*1024 + threadIdx.x;
  if (p >= NPRED) return;
  u64 k = sorted[b*NPRED + p];
  u32 bin = (u32)(k >> 52);
  u32 base = gsuffix[b*NBINS + bin];
  if (base >= KEEP_PRE) return;              // definitely not in top-6000
  u32 cnt = ghist[b*NBINS + bin];
  u32 r = base;
  const u64* sb = sorted + b*NPRED;
  for (u32 q = base; q < base + cnt; ++q) r += (sb[q] > k) ? 1u : 0u;
  if (r < KEEP_PRE) {
    u32 idx = ~(u32)k;
    props[b*KEEP_PRE + r] = boxes[b*NPRED + idx];
  }
}

// ---------------------------------------------------------------------------
// Kernel 5: fused greedy NMS + output. One wave per batch. Kept set (<=300
// boxes) lives in registers: lane l owns kept indices c with c%64==l at static
// slot c/64 (5 slots). keep[i] <=> no kept j<i with IoU>0.7 — exact greedy.
// Zero-init slots can never suppress (inter==0, union>=0 -> 0 > pos is false).
// Candidate broadcast via v_readlane (uniform index), not ds_bpermute.
// ---------------------------------------------------------------------------
__device__ __forceinline__ float bcast(float v, int srcLane) {
  return __int_as_float(__builtin_amdgcn_readlane(__float_as_int(v), srcLane));
}

__device__ __forceinline__ bool iou_sup(float kx1, float ky1, float kx2, float ky2,
                                        float ka, float cx1, float cy1,
                                        float cx2, float cy2, float ca) {
  // identical op structure to the validated round-0 mask kernel (fmax/fmin/add
  // all exactly commutative -> bit-identical suppress decisions)
  float wx = fmaxf(fminf(kx2, cx2) - fmaxf(kx1, cx1), 0.f);
  float wy = fmaxf(fminf(ky2, cy2) - fmaxf(ky1, cy1), 0.f);
  float inter = wx * wy;
  float un = ka + ca - inter;
  return inter > 0.7f * fmaxf(un, 1e-9f);
}

__global__ void __launch_bounds__(64) nms_kernel(
    const float4* __restrict__ props, const u32* __restrict__ nposg,
    float4* __restrict__ out)
{
  const int b = blockIdx.x;
  const int lane = threadIdx.x;
  const float4* pb = props + b*KEEP_PRE;
  float4* ob = out + b*KEEP_POST;
  const int npos = (int)nposg[b];
  const float4 zero = make_float4(0.f, 0.f, 0.f, 0.f);

  // kept set: 5 static register slots per lane (cnt<=300 => slot = c/64 in 0..4)
  float4 k0=zero,k1=zero,k2=zero,k3=zero,k4=zero;
  float a0=0.f,a1=0.f,a2=0.f,a3=0.f,a4=0.f;
  int cnt = 0;

  float4 curb = pb[lane];                       // rows 0..63 (coalesced)
  float4 nxtb = zero;

  for (int base = 0; base < KEEP_PRE && cnt < KEEP_POST; base += 64) {
    {
      int idx = base + 64 + lane;
      nxtb = (idx < KEEP_PRE) ? pb[idx] : zero; // prefetch next 64 candidates
    }
    for (int r = 0; r < 64; ++r) {
      int i = base + r;
      if (i >= KEEP_PRE) break;
      float cx1 = bcast(curb.x, r);
      float cy1 = bcast(curb.y, r);
      float cx2 = bcast(curb.z, r);
      float cy2 = bcast(curb.w, r);
      float ca = fmaxf(cx2 - cx1, 0.f) * fmaxf(cy2 - cy1, 0.f);

      bool sup = iou_sup(k0.x,k0.y,k0.z,k0.w,a0, cx1,cy1,cx2,cy2,ca);
      if (cnt > 64)  sup |= iou_sup(k1.x,k1.y,k1.z,k1.w,a1, cx1,cy1,cx2,cy2,ca);
      if (cnt > 128) sup |= iou_sup(k2.x,k2.y,k2.z,k2.w,a2, cx1,cy1,cx2,cy2,ca);
      if (cnt > 192) sup |= iou_sup(k3.x,k3.y,k3.z,k3.w,a3, cx1,cy1,cx2,cy2,ca);
      if (cnt > 256) sup |= iou_sup(k4.x,k4.y,k4.z,k4.w,a4, cx1,cy1,cx2,cy2,ca);

      if (__any((int)sup)) continue;            // suppressed by an earlier keep

      // keep candidate i as kept #cnt
      if (lane == (cnt & 63)) {
        float4 bb = make_float4(cx1, cy1, cx2, cy2);
        switch (cnt >> 6) {                     // uniform, static slots
          case 0: k0 = bb; a0 = ca; break;
          case 1: k1 = bb; a1 = ca; break;
          case 2: k2 = bb; a2 = ca; break;
          case 3: k3 = bb; a3 = ca; break;
          default: k4 = bb; a4 = ca; break;
        }
      }
      if (lane == 0) {
        bool conf = (i < npos);                 // sigmoid(p)>0.5 <=> p>0 <=> rank<npos
        ob[cnt] = conf ? make_float4(cx1, cy1, cx2, cy2) : zero;
      }
      ++cnt;
      if (cnt >= KEEP_POST) break;
    }
    curb = nxtb;
  }
  // zero-fill tail rows (d_out is poisoned before every timed launch)
  for (int k = cnt + lane; k < KEEP_POST; k += 64) ob[k] = zero;
}

extern "C" void kernel_launch(void* const* d_in, const int* in_sizes, int n_in,
                              void* d_out, int out_size, void* d_ws, size_t ws_size,
                              hipStream_t stream) {
  const float* preds = (const float*)d_in[0];
  const float* regs  = (const float*)d_in[1];
  const int* ih      = (const int*)d_in[2];
  const int* iw      = (const int*)d_in[3];

  if (ws_size < (size_t)WS_NEEDED) return;  // loud failure (poisoned out)

  char* ws = (char*)d_ws;
  u64*    keys    = (u64*)   (ws + OFF_KEYS);
  float4* boxes   = (float4*)(ws + OFF_BOXES);
  u32*    ghist   = (u32*)   (ws + OFF_HIST);
  u32*    nposg   = (u32*)   (ws + OFF_NPOS);
  u32*    gsuffix = (u32*)   (ws + OFF_SUFFIX);
  u32*    gcursor = (u32*)   (ws + OFF_CURSOR);
  u64*    sorted  = (u64*)   (ws + OFF_SORTED);
  float4* props   = (float4*)(ws + OFF_PROPS);

  // zero hist + npos in one shot (they are contiguous)
  hipMemsetAsync(ghist, 0, BS*NBINS*sizeof(u32) + 16, stream);

  dim3 g21((NPRED + 1023)/1024, BS);   // (21, 4)
  prep_kernel<<<g21, 1024, 0, stream>>>(preds, regs, ih, iw, keys, boxes, ghist, nposg);
  suffix_kernel<<<dim3(BS), 1024, 0, stream>>>(ghist, gsuffix, gcursor);
  scatter_kernel<<<g21, 1024, 0, stream>>>(keys, gcursor, sorted);
  rank_kernel<<<g21, 1024, 0, stream>>>(sorted, gsuffix, ghist, boxes, props);
  nms_kernel<<<dim3(BS), 64, 0, stream>>>(props, nposg, (float4*)d_out);
}

// Round 3
// 285.101 us; speedup vs baseline: 1.1488x; 1.1488x over previous
//
#include <hip/hip_runtime.h>
#include <stdint.h>

typedef unsigned long long u64;
typedef unsigned int u32;

#define FH 37
#define FW 62
#define NA 9
#define NPRED (FH*FW*NA)   // 20646
#define BS 4
#define KEEP_PRE 6000
#define KEEP_POST 300
#define NBINS 4096
#define NBLK ((KEEP_PRE + 63) / 64)   // 94

// ws layout (bytes), all 16B aligned
#define OFF_KEYS    0u
#define OFF_BOXES   660672u
#define OFF_HIST    1982016u
#define OFF_NPOS    2047552u
#define OFF_SUFFIX  2047568u
#define OFF_CURSOR  2113104u
#define OFF_SORTED  2178640u
#define OFF_PROPS   2839312u
#define WS_NEEDED   3223312u

// ---------------------------------------------------------------------------
// Kernel 1: keys (order-exact sort key from pred bits) + box decode + histogram
// + per-batch positive-pred count (conf bit == rank < npos)
// ---------------------------------------------------------------------------
__global__ void __launch_bounds__(1024) prep_kernel(
    const float* __restrict__ preds, const float* __restrict__ regs,
    const int* __restrict__ ih, const int* __restrict__ iw,
    u64* __restrict__ keys, float4* __restrict__ boxes, u32* __restrict__ ghist,
    u32* __restrict__ nposg)
{
  __shared__ u32 lh[NBINS];
  const int tid = threadIdx.x;
  const int b = blockIdx.y;
  for (int v = tid; v < NBINS; v += 1024) lh[v] = 0;
  __syncthreads();
  const int n = blockIdx.x * 1024 + tid;
  const bool valid = (n < NPRED);
  float p = valid ? preds[b*NPRED + n] : -1.0f;

  // all 1024 lanes active here: wave-level count of strictly-positive preds
  u64 posmask = __ballot(valid && (p > 0.0f));
  if ((tid & 63) == 0) atomicAdd(&nposg[b], (u32)__popcll(posmask));

  if (valid) {
    u32 u = __float_as_uint(p);
    u32 m = (u & 0x80000000u) ? ~u : (u | 0x80000000u);  // order-preserving map
    u64 key = ((u64)m << 32) | (u32)(~(u32)n);           // tiebreak: lower idx first
    keys[b*NPRED + n] = key;
    atomicAdd(&lh[m >> 20], 1u);

    // decode box, mirroring reference op order
    int a = n % NA;
    int cell = n / NA;
    int x = cell % FW;
    int y = cell / FW;
    int si = a % 3, ri = a / 3;
    float s = (si==0) ? 8.f : ((si==1) ? 16.f : 32.f);
    float r = (ri==0) ? 0.5f : ((ri==1) ? 1.0f : 2.0f);
    float aw = s * sqrtf(1.0f / r);
    float ah = s * sqrtf(r);
    float gx = (float)x * 16.f, gy = (float)y * 16.f;
    float x1d = gx - 0.5f*aw, x2d = gx + 0.5f*aw;
    float y1d = gy - 0.5f*ah, y2d = gy + 0.5f*ah;
    float w = x2d - x1d, h = y2d - y1d;
    float cx = x1d + 0.5f*w, cy = y1d + 0.5f*h;
    float4 d = reinterpret_cast<const float4*>(regs)[b*NPRED + n];
    float pcx = d.x*w + cx, pcy = d.y*h + cy;
    float pw = expf(d.z)*w, ph = expf(d.w)*h;
    float W = (float)(*iw), H = (float)(*ih);
    float bx1 = fminf(fmaxf(pcx - 0.5f*pw, 0.f), W);
    float by1 = fminf(fmaxf(pcy - 0.5f*ph, 0.f), H);
    float bx2 = fminf(fmaxf(pcx + 0.5f*pw, 0.f), W);
    float by2 = fminf(fmaxf(pcy + 0.5f*ph, 0.f), H);
    boxes[b*NPRED + n] = make_float4(bx1, by1, bx2, by2);
  }
  __syncthreads();
  for (int v = tid; v < NBINS; v += 1024) {
    u32 c = lh[v];
    if (c) atomicAdd(&ghist[b*NBINS + v], c);
  }
}

// ---------------------------------------------------------------------------
// Kernel 2: per-batch suffix sum over bins (count of elements in higher bins)
// ---------------------------------------------------------------------------
__global__ void __launch_bounds__(1024) suffix_kernel(
    const u32* __restrict__ ghist, u32* __restrict__ gsuffix, u32* __restrict__ gcursor)
{
  __shared__ u32 vals[NBINS];
  __shared__ u32 psum[1024];
  const int b = blockIdx.x, t = threadIdx.x;
  for (int v = t; v < NBINS; v += 1024) vals[v] = ghist[b*NBINS + v];
  __syncthreads();
  u32 a0 = vals[4*t], a1 = vals[4*t+1], a2 = vals[4*t+2], a3 = vals[4*t+3];
  u32 s = a0 + a1 + a2 + a3;
  psum[t] = s;
  __syncthreads();
  for (int off = 1; off < 1024; off <<= 1) {
    u32 add = (t + off < 1024) ? psum[t + off] : 0;
    __syncthreads();
    psum[t] += add;
    __syncthreads();
  }
  u32 tail = psum[t] - s;        // sum over threads > t
  u32 s3 = tail;
  u32 s2 = s3 + a3;
  u32 s1 = s2 + a2;
  u32 s0 = s1 + a1;
  int base = b*NBINS + 4*t;
  gsuffix[base+0]=s0; gsuffix[base+1]=s1; gsuffix[base+2]=s2; gsuffix[base+3]=s3;
  gcursor[base+0]=s0; gcursor[base+1]=s1; gcursor[base+2]=s2; gcursor[base+3]=s3;
}

// ---------------------------------------------------------------------------
// Kernel 3: scatter keys into bin-ordered array (counting sort; in-bin order
// irrelevant — exact rank computed by comparison later)
// ---------------------------------------------------------------------------
__global__ void __launch_bounds__(1024) scatter_kernel(
    const u64* __restrict__ keys, u32* __restrict__ gcursor, u64* __restrict__ sorted)
{
  const int b = blockIdx.y;
  const int n = blockIdx.x*1024 + threadIdx.x;
  if (n >= NPRED) return;
  u64 k = keys[b*NPRED + n];
  u32 bin = (u32)(k >> 52);
  u32 pos = atomicAdd(&gcursor[b*NBINS + bin], 1u);
  sorted[b*NPRED + pos] = k;
}

// ---------------------------------------------------------------------------
// Kernel 4: exact rank (bin base + in-bin count of larger keys); gather props
// ---------------------------------------------------------------------------
__global__ void __launch_bounds__(1024) rank_kernel(
    const u64* __restrict__ sorted, const u32* __restrict__ gsuffix,
    const u32* __restrict__ ghist, const float4* __restrict__ boxes,
    float4* __restrict__ props)
{
  const int b = blockIdx.y;
  const int p = blockIdx.x*1024 + threadIdx.x;
  if (p >= NPRED) return;
  u64 k = sorted[b*NPRED + p];
  u32 bin = (u32)(k >> 52);
  u32 base = gsuffix[b*NBINS + bin];
  if (base >= KEEP_PRE) return;              // definitely not in top-6000
  u32 cnt = ghist[b*NBINS + bin];
  u32 r = base;
  const u64* sb = sorted + b*NPRED;
  for (u32 q = base; q < base + cnt; ++q) r += (sb[q] > k) ? 1u : 0u;
  if (r < KEEP_PRE) {
    u32 idx = ~(u32)k;
    props[b*KEEP_PRE + r] = boxes[b*NPRED + idx];
  }
}

// ---------------------------------------------------------------------------
// Kernel 5: fused greedy NMS + output. One wave per batch, 64 candidates per
// block-iteration (one per lane). Kept list (<=300) lives in LDS.
//   Phase A: lane-parallel check of each candidate vs ALL kept so far
//            (uniform-address LDS reads broadcast for free).
//   Phase B: intra-block 64x64 suppression columns via readlane + ballot;
//            lane r keeps column r (bits m>r it suppresses).
//   Closure: scalar bit-sweep alive64: j=ctz -> keep j -> alive64 &= ~col_j.
// Exactly greedy NMS; decision math identical to validated round-0/1 kernels.
// ---------------------------------------------------------------------------
__device__ __forceinline__ float bcast(float v, int srcLane) {
  return __int_as_float(__builtin_amdgcn_readlane(__float_as_int(v), srcLane));
}
__device__ __forceinline__ u64 readlane64(u64 v, int srcLane) {
  u32 lo = __builtin_amdgcn_readlane((u32)v, srcLane);
  u32 hi = __builtin_amdgcn_readlane((u32)(v >> 32), srcLane);
  return ((u64)hi << 32) | lo;
}

__device__ __forceinline__ bool iou_sup(float kx1, float ky1, float kx2, float ky2,
                                        float ka, float cx1, float cy1,
                                        float cx2, float cy2, float ca) {
  float wx = fmaxf(fminf(kx2, cx2) - fmaxf(kx1, cx1), 0.f);
  float wy = fmaxf(fminf(ky2, cy2) - fmaxf(ky1, cy1), 0.f);
  float inter = wx * wy;
  float un = ka + ca - inter;
  return inter > 0.7f * fmaxf(un, 1e-9f);
}

__global__ void __launch_bounds__(64) nms_kernel(
    const float4* __restrict__ props, const u32* __restrict__ nposg,
    float4* __restrict__ out)
{
  const int b = blockIdx.x;
  const int lane = threadIdx.x;
  const float4* pb = props + b*KEEP_PRE;
  float4* ob = out + b*KEEP_POST;
  const int npos = (int)nposg[b];
  const float4 zero = make_float4(0.f, 0.f, 0.f, 0.f);

  __shared__ float4 kbox[KEEP_POST];
  __shared__ float  karea[KEEP_POST];

  int cnt = 0;
  float4 cur = pb[lane];                        // block 0 candidates

  for (int blk = 0; blk < NBLK && cnt < KEEP_POST; ++blk) {
    const int base = blk * 64;
    // prefetch next block's candidates (hides HBM/L2 latency under phases A/B)
    float4 nxt = zero;
    {
      int nidx = base + 64 + lane;
      if (nidx < KEEP_PRE) nxt = pb[nidx];
    }

    const int i = base + lane;
    float ca = fmaxf(cur.z - cur.x, 0.f) * fmaxf(cur.w - cur.y, 0.f);
    bool alive = (i < KEEP_PRE);

    // -------- Phase A: my candidate vs all kept so far (LDS broadcast) -----
    #pragma unroll 4
    for (int k = 0; k < cnt; ++k) {
      float4 kb = kbox[k];
      float kA = karea[k];
      alive = alive & !iou_sup(kb.x, kb.y, kb.z, kb.w, kA,
                               cur.x, cur.y, cur.z, cur.w, ca);
    }
    u64 A = __ballot((int)alive);

    if (A) {
      // -------- Phase B: intra-block suppression columns ------------------
      u64 colmask = 0;                          // lane l: bits m>l it suppresses
      for (int r = 0; r < 63; ++r) {
        if (!((A >> r) & 1ull)) continue;       // dead rows are never kept
        float rx1 = bcast(cur.x, r);
        float ry1 = bcast(cur.y, r);
        float rx2 = bcast(cur.z, r);
        float ry2 = bcast(cur.w, r);
        float ra  = bcast(ca, r);
        bool sup = (lane > r) && iou_sup(rx1, ry1, rx2, ry2, ra,
                                         cur.x, cur.y, cur.z, cur.w, ca);
        u64 bm = __ballot((int)sup);
        if (lane == r) colmask = bm;
      }

      // -------- Closure: scalar greedy bit-sweep --------------------------
      u64 alive64 = A;
      while (alive64 && cnt < KEEP_POST) {
        int j = (int)__builtin_ctzll(alive64);
        alive64 &= alive64 - 1;                 // clear bit j
        alive64 &= ~readlane64(colmask, j);     // suppress j's victims
        float x1 = bcast(cur.x, j);
        float y1 = bcast(cur.y, j);
        float x2 = bcast(cur.z, j);
        float y2 = bcast(cur.w, j);
        float aj = bcast(ca, j);
        if (lane == 0) {
          kbox[cnt] = make_float4(x1, y1, x2, y2);
          karea[cnt] = aj;
          bool conf = (base + j) < npos;        // sigmoid(p)>0.5 <=> rank<npos
          ob[cnt] = conf ? make_float4(x1, y1, x2, y2) : zero;
        }
        ++cnt;
      }
    }
    __syncthreads();   // make lane0's LDS kept-list writes visible (1 wave: cheap)
    cur = nxt;
  }
  // zero-fill tail rows (d_out is poisoned before every timed launch)
  for (int k2 = cnt + lane; k2 < KEEP_POST; k2 += 64) ob[k2] = zero;
}

extern "C" void kernel_launch(void* const* d_in, const int* in_sizes, int n_in,
                              void* d_out, int out_size, void* d_ws, size_t ws_size,
                              hipStream_t stream) {
  const float* preds = (const float*)d_in[0];
  const float* regs  = (const float*)d_in[1];
  const int* ih      = (const int*)d_in[2];
  const int* iw      = (const int*)d_in[3];

  if (ws_size < (size_t)WS_NEEDED) return;  // loud failure (poisoned out)

  char* ws = (char*)d_ws;
  u64*    keys    = (u64*)   (ws + OFF_KEYS);
  float4* boxes   = (float4*)(ws + OFF_BOXES);
  u32*    ghist   = (u32*)   (ws + OFF_HIST);
  u32*    nposg   = (u32*)   (ws + OFF_NPOS);
  u32*    gsuffix = (u32*)   (ws + OFF_SUFFIX);
  u32*    gcursor = (u32*)   (ws + OFF_CURSOR);
  u64*    sorted  = (u64*)   (ws + OFF_SORTED);
  float4* props   = (float4*)(ws + OFF_PROPS);

  // zero hist + npos in one shot (they are contiguous)
  hipMemsetAsync(ghist, 0, BS*NBINS*sizeof(u32) + 16, stream);

  dim3 g21((NPRED + 1023)/1024, BS);   // (21, 4)
  prep_kernel<<<g21, 1024, 0, stream>>>(preds, regs, ih, iw, keys, boxes, ghist, nposg);
  suffix_kernel<<<dim3(BS), 1024, 0, stream>>>(ghist, gsuffix, gcursor);
  scatter_kernel<<<g21, 1024, 0, stream>>>(keys, gcursor, sorted);
  rank_kernel<<<g21, 1024, 0, stream>>>(sorted, gsuffix, ghist, boxes, props);
  nms_kernel<<<dim3(BS), 64, 0, stream>>>(props, nposg, (float4*)d_out);
}